// Round 6
// baseline (296.355 us; speedup 1.0000x reference)
//
#include <hip/hip_runtime.h>
#include <math.h>

#define B 4
#define L 2048
#define E 1024
#define H 16
#define HD 64
#define MROWS (B*L)      // 8192
#define E3 (3*E)         // 3072

using bf16x8   = __attribute__((ext_vector_type(8))) short;
using f16x8    = __attribute__((ext_vector_type(8))) _Float16;
using floatx4  = __attribute__((ext_vector_type(4))) float;
using floatx16 = __attribute__((ext_vector_type(16))) float;

__device__ inline ushort f2bf(float x) {
    uint u = __float_as_uint(x);
    u += 0x7FFF + ((u >> 16) & 1);     // RNE
    return (ushort)(u >> 16);
}
__device__ inline float bf2f(ushort h) { return __uint_as_float(((uint)h) << 16); }
__device__ inline ushort f2h(float x) { _Float16 h = (_Float16)x; return *(ushort*)&h; }

#if __has_builtin(__builtin_amdgcn_exp2f)
#define EXP2F(x) __builtin_amdgcn_exp2f(x)
#else
#define EXP2F(x) exp2f(x)
#endif

__device__ inline void async16(const void* g, void* l) {
    __builtin_amdgcn_global_load_lds(
        (const __attribute__((address_space(1))) uint*)g,
        (__attribute__((address_space(3))) uint*)l, 16, 0, 0);
}

// pack two fp32 -> {bf16(odd),bf16(even)} with RTZ in one v_perm
__device__ inline uint pack_rtz(float odd, float even) {
    return __builtin_amdgcn_perm(__float_as_uint(odd), __float_as_uint(even), 0x07060302u);
}

// ------------------------------------------------------------------
// fused fp32 -> fp16 convert of x | Wqkv | Wout (one launch)
// ------------------------------------------------------------------
#define N1Q ((size_t)MROWS * E / 4)        // x quads
#define N2Q ((size_t)E3 * E / 4)           // Wqkv quads
#define N3Q ((size_t)E * E / 4)            // Wout quads
__global__ __launch_bounds__(256) void cvt_all(
        const float* __restrict__ x, const float* __restrict__ wq,
        const float* __restrict__ wo, ushort* __restrict__ x16,
        ushort* __restrict__ wq16, ushort* __restrict__ wo16)
{
    size_t i = (size_t)blockIdx.x * 256 + threadIdx.x;
    const float* src; ushort* dst; size_t j;
    if (i < N1Q)                  { src = x;  dst = x16;  j = i; }
    else if (i < N1Q + N2Q)       { src = wq; dst = wq16; j = i - N1Q; }
    else                          { src = wo; dst = wo16; j = i - N1Q - N2Q; }
    float4 v = ((const float4*)src)[j];
    ushort4 o;
    o.x = f2h(v.x); o.y = f2h(v.y); o.z = f2h(v.z); o.w = f2h(v.w);
    ((ushort4*)dst)[j] = o;
}

// ------------------------------------------------------------------
// Single-pass fp16 MFMA GEMM (R0 harness-proven structure, unchanged):
// async double-buffered K-loop, 128x128 tile, BK=32, 256 thr = 4 waves
// of 64x64. ncol0 = global column offset of this launch's B-panel
// (B16 passed pre-offset by ncol0*Kdim); at ncol0=0 the epilogue
// arithmetic is byte-identical to the proven kernel.
// MODE 1 epilogue: bias + RoPE -> swizzled q/k + sigma'd v^T (bf16).
// MODE 2 epilogue: bias, fp32 row-major out.
// ------------------------------------------------------------------
template<int MODE>
__global__ __launch_bounds__(256) void gemm_f16(
        const ushort* __restrict__ A16, const ushort* __restrict__ B16,
        const float* __restrict__ bias, float* __restrict__ Cf,
        ushort* __restrict__ qh, ushort* __restrict__ kh, ushort* __restrict__ vT,
        const float* __restrict__ cosT, const float* __restrict__ sinT,
        int ncol0, int Ndim, int Kdim)
{
    __shared__ ushort lds[2][8192];   // dbuf of (A tile | B tile)

    const int tid = threadIdx.x;
    const int w = tid >> 6, lane = tid & 63;
    const int g = lane >> 4, c = lane & 15;
    const int m0 = blockIdx.y * 128, n0 = blockIdx.x * 128;
    const int wm = w & 1, wn = w >> 1;

    const int rl0 = lane >> 2;
    const int jsw = (lane & 3) ^ ((lane >> 3) & 3);
    const ushort* gbase = (w < 2) ? A16 + (size_t)(m0 + 64 * (w & 1)) * Kdim
                                  : B16 + (size_t)(n0 + 64 * (w & 1)) * Kdim;
    const ushort* lanesrc = gbase + (size_t)rl0 * Kdim + jsw * 8;
    const int ldoff = (w >> 1) * 4096 + (w & 1) * 2048;

    floatx4 acc[4][4];
#pragma unroll
    for (int a = 0; a < 4; ++a)
#pragma unroll
        for (int bq = 0; bq < 4; ++bq) acc[a][bq] = (floatx4){0.f, 0.f, 0.f, 0.f};

    const int swz  = (g ^ ((c >> 1) & 3)) * 8;
    const int arow = wm * 2048 + c * 32;
    const int brow = 4096 + wn * 2048 + c * 32;

    // prologue: stage k-tile 0 into buf 0
#pragma unroll
    for (int p = 0; p < 4; ++p)
        async16(lanesrc + (size_t)p * 16 * Kdim, &lds[0][ldoff + p * 512]);

    const int NK = Kdim >> 5;   // 32
    for (int kk = 0; kk < NK; ++kk) {
        const int pb = kk & 1;
        __syncthreads();   // drains the loads targeting buf pb; syncs waves

        // prefetch k-tile kk+1 into the other buffer (flies during compute)
        if (kk + 1 < NK) {
            const ushort* ns = lanesrc + (size_t)(kk + 1) * 32;
#pragma unroll
            for (int p = 0; p < 4; ++p)
                async16(ns + (size_t)p * 16 * Kdim, &lds[pb ^ 1][ldoff + p * 512]);
        }

        const ushort* cur = &lds[pb][0];
        f16x8 af[4], bf[4];
#pragma unroll
        for (int t = 0; t < 4; ++t) {
            af[t] = *(const f16x8*)&cur[arow + t * 512 + swz];
            bf[t] = *(const f16x8*)&cur[brow + t * 512 + swz];
        }
#pragma unroll
        for (int mt = 0; mt < 4; ++mt)
#pragma unroll
            for (int nt = 0; nt < 4; ++nt)
                acc[mt][nt] = __builtin_amdgcn_mfma_f32_16x16x32_f16(af[mt], bf[nt], acc[mt][nt], 0, 0, 0);
    }

    // ---- epilogue; C/D: row = g*4+i, col = c (per 16x16 tile) ----
    const int colbase = ncol0 + n0 + wn * 64;
#pragma unroll
    for (int mt = 0; mt < 4; ++mt) {
        const int rowb = m0 + wm * 64 + mt * 16 + g * 4;
        if constexpr (MODE == 2) {
#pragma unroll
            for (int i = 0; i < 4; ++i) {
                const int row = rowb + i;
#pragma unroll
                for (int nt = 0; nt < 4; ++nt) {
                    const int col = colbase + nt * 16 + c;
                    Cf[(size_t)row * Ndim + col] = acc[mt][nt][i] + bias[col];
                }
            }
        } else {
            const int sec = colbase >> 10;             // 0=q 1=k 2=v
            const int hg  = (colbase & 1023) >> 6;
#pragma unroll
            for (int i = 0; i < 4; ++i) {
                const int row = rowb + i;
                const int bb = row >> 11;
                const int l  = row & (L - 1);
                if (sec < 2) {
                    ushort* dst = (sec == 0 ? qh : kh) + ((size_t)(bb * H + hg) * L + l) * HD;
                    const int sw = l & 7;
                    // q carries softmax scale AND log2e for the exp2 softmax
                    const float qs = (sec == 0) ? 0.18033688f : 1.0f;
#pragma unroll
                    for (int nt = 0; nt < 2; ++nt) {
                        const int d  = nt * 16 + c;
                        const int d2 = d + 32;
                        float v1 = acc[mt][nt][i]     + bias[colbase + d];
                        float v2 = acc[mt][nt + 2][i] + bias[colbase + d2];
                        float cs = cosT[l * 32 + d], sn = sinT[l * 32 + d];
                        dst[(((d  >> 3) ^ sw) << 3) | (d  & 7)] = f2bf((v1 * cs - v2 * sn) * qs);
                        dst[(((d2 >> 3) ^ sw) << 3) | (d2 & 7)] = f2bf((v1 * sn + v2 * cs) * qs);
                    }
                } else {
                    // sigma: swap bits 2,3 of kpos; then group-swizzle by d&7
                    const int lp = (l & ~12) | ((l & 4) << 1) | ((l & 8) >> 1);
                    const int intile = ((((lp >> 3) & 7)) << 3);
#pragma unroll
                    for (int nt = 0; nt < 4; ++nt) {
                        const int d = nt * 16 + c;
                        float v = acc[mt][nt][i] + bias[colbase + d];
                        size_t idx = ((size_t)(bb * H + hg) * HD + d) * L
                                   + (l & ~63) + (intile ^ ((d & 7) << 3)) + (lp & 7);
                        vT[idx] = f2bf(v);
                    }
                }
            }
        }
    }
}

// ------------------------------------------------------------------
// Flash attention v4 + T5 setprio around QK/PV MFMA clusters
// (m191: +4-7% on attention). Otherwise unchanged from proven kernel.
// ------------------------------------------------------------------
__global__ __launch_bounds__(256, 4) void flash_mfma4(
        const ushort* __restrict__ qh, const ushort* __restrict__ kh,
        const ushort* __restrict__ vT, ushort* __restrict__ attn16)
{
    __shared__ ushort Ks[2][4096];
    __shared__ ushort Vt[2][4096];

    const int tid  = threadIdx.x;
    const int w    = tid >> 6;
    const int lane = tid & 63;
    const int h    = lane >> 5;
    const int n    = lane & 31;
    const int b    = blockIdx.x >> 4;
    const int hd   = blockIdx.x & 15;
    const int q0   = blockIdx.y * 128;

    const ushort* khead = kh + (size_t)(b * H + hd) * L * HD;
    const ushort* vhead = vT + (size_t)(b * H + hd) * HD * L;

    const int q = q0 + 32 * w + n;
    const ushort* qrow = qh + ((size_t)(b * H + hd) * L + q) * HD;
    bf16x8 aq[4];
#pragma unroll
    for (int kd = 0; kd < 4; ++kd)
        aq[kd] = *(const bf16x8*)&qrow[((2 * kd + h) ^ (q & 7)) << 3];

    const int wk = w & 1;
    const ushort* ksrc = khead + (size_t)(32 * wk) * 64 + lane * 8;
    const ushort* vsrc = vhead + (size_t)(32 * wk + (lane >> 3)) * L + (lane & 7) * 8;

    const int NIT = L / 64;   // 32
    if (w < 2) {
#pragma unroll
        for (int p = 0; p < 4; ++p)
            async16(ksrc + p * 512, &Ks[0][32 * wk * 64 + p * 512]);
    } else {
#pragma unroll
        for (int p = 0; p < 4; ++p)
            async16(vsrc + (size_t)p * 8 * L, &Vt[0][32 * wk * 64 + p * 512]);
    }

    float l_i = 0.f;
    floatx16 o[2];
    o[0] = (floatx16)(0.f);
    o[1] = (floatx16)(0.f);

    for (int it = 0; it < NIT; ++it) {
        const int p = it & 1;
        __syncthreads();

        if (it + 1 < NIT) {
            if (w < 2) {
                const ushort* s = ksrc + (size_t)(it + 1) * 4096;
#pragma unroll
                for (int pp = 0; pp < 4; ++pp)
                    async16(s + pp * 512, &Ks[p ^ 1][32 * wk * 64 + pp * 512]);
            } else {
                const ushort* s = vsrc + (size_t)(it + 1) * 64;
#pragma unroll
                for (int pp = 0; pp < 4; ++pp)
                    async16(s + (size_t)pp * 8 * L, &Vt[p ^ 1][32 * wk * 64 + pp * 512]);
            }
        }

        const ushort* KsC = Ks[p];
        const ushort* VtC = Vt[p];

#pragma unroll
        for (int js = 0; js < 2; ++js) {
            floatx16 s = (floatx16)(-16.0f);
            __builtin_amdgcn_s_setprio(1);
#pragma unroll
            for (int kd = 0; kd < 4; ++kd) {
                bf16x8 kf = *(const bf16x8*)&KsC[(32 * js + n) * 64 + (((2 * kd + h) ^ (n & 7)) << 3)];
                s = __builtin_amdgcn_mfma_f32_32x32x16_bf16(kf, aq[kd], s, 0, 0, 0);
            }
            __builtin_amdgcn_s_setprio(0);

            float pv[16];
            float rs = 0.f;
#pragma unroll
            for (int rr = 0; rr < 4; ++rr) {
                float p0 = EXP2F(s[4 * rr + 0]);
                float p1 = EXP2F(s[4 * rr + 1]);
                float p2 = EXP2F(s[4 * rr + 2]);
                float p3 = EXP2F(s[4 * rr + 3]);
                pv[4 * rr + 0] = p0; pv[4 * rr + 1] = p1;
                pv[4 * rr + 2] = p2; pv[4 * rr + 3] = p3;
                rs += (p0 + p1) + (p2 + p3);
            }
            l_i += rs;

#pragma unroll
            for (int f = 0; f < 2; ++f) {
                uint bu[4];
                bu[0] = pack_rtz(pv[8 * f + 1], pv[8 * f + 0]);
                bu[1] = pack_rtz(pv[8 * f + 3], pv[8 * f + 2]);
                bu[2] = pack_rtz(pv[8 * f + 5], pv[8 * f + 4]);
                bu[3] = pack_rtz(pv[8 * f + 7], pv[8 * f + 6]);
                bf16x8 bp = *(const bf16x8*)&bu[0];
                __builtin_amdgcn_s_setprio(1);
#pragma unroll
                for (int nt = 0; nt < 2; ++nt) {
                    bf16x8 vf = *(const bf16x8*)&VtC[(32 * nt + n) * 64 + (((4 * js + 2 * f + h) ^ (n & 7)) << 3)];
                    o[nt] = __builtin_amdgcn_mfma_f32_32x32x16_bf16(vf, bp, o[nt], 0, 0, 0);
                }
                __builtin_amdgcn_s_setprio(0);
            }
        }
    }

    const float l_tot = l_i + __shfl_xor(l_i, 32, 64);
    const float inv = 1.f / l_tot;
    const size_t rowbase = ((size_t)(b * L + q)) * E + hd * HD;
#pragma unroll
    for (int nt = 0; nt < 2; ++nt)
#pragma unroll
        for (int rr = 0; rr < 4; ++rr) {
            const int d0 = 32 * nt + 8 * rr + 4 * h;
            ushort h0 = f2h(o[nt][4 * rr + 0] * inv);
            ushort h1 = f2h(o[nt][4 * rr + 1] * inv);
            ushort h2 = f2h(o[nt][4 * rr + 2] * inv);
            ushort h3 = f2h(o[nt][4 * rr + 3] * inv);
            uint2 hw;
            hw.x = (uint)h0 | ((uint)h1 << 16);
            hw.y = (uint)h2 | ((uint)h3 << 16);
            *(uint2*)&attn16[rowbase + d0] = hw;
        }
}

extern "C" void kernel_launch(void* const* d_in, const int* in_sizes, int n_in,
                              void* d_out, int out_size, void* d_ws, size_t ws_size,
                              hipStream_t stream) {
    const float* x    = (const float*)d_in[0];
    const float* cosT = (const float*)d_in[1];
    const float* sinT = (const float*)d_in[2];
    const float* Wqkv = (const float*)d_in[3];
    const float* bqkv = (const float*)d_in[4];
    const float* Wout = (const float*)d_in[5];
    const float* bout = (const float*)d_in[6];
    float* out = (float*)d_out;

    const size_t NX = (size_t)MROWS * E;
    ushort* us   = (ushort*)d_ws;
    ushort* qh   = us;                        // [B,H,L,HD] roped+scaled q (bf16, swz)
    ushort* kh   = us + NX;                   // [B,H,L,HD] roped k (bf16, swz)
    ushort* vTp  = us + 2 * NX;               // [B,H,HD,L] v^T (bf16, sigma+swz)
    ushort* x16  = us + 3 * NX;               // x fp16
    ushort* at16 = us + 4 * NX;               // attn fp16
    ushort* wq16 = us + 5 * NX;               // Wqkv fp16
    ushort* wo16 = wq16 + (size_t)E3 * E;     // Wout fp16

    const int cvt_blocks = (int)((N1Q + N2Q + N3Q + 255) / 256);
    cvt_all<<<cvt_blocks, 256, 0, stream>>>(x, Wqkv, Wout, x16, wq16, wo16);

    // QKV split into two launches (same total work; lowers the top-5
    // cutoff so flash/gemm2 durations become visible in rocprof):
    //   q,k columns [0,2048): grid (16,64) = 1024 blocks
    gemm_f16<1><<<dim3(2048 / 128, MROWS / 128), 256, 0, stream>>>(
        x16, wq16, bqkv, nullptr, qh, kh, vTp, cosT, sinT, 0, E3, E);
    //   v columns [2048,3072): grid (8,64) = 512 blocks
    gemm_f16<1><<<dim3(1024 / 128, MROWS / 128), 256, 0, stream>>>(
        x16, wq16 + (size_t)2048 * E, bqkv, nullptr, qh, kh, vTp, cosT, sinT, 2048, E3, E);

    flash_mfma4<<<dim3(B * H, L / 128), 256, 0, stream>>>(qh, kh, vTp, at16);

    gemm_f16<2><<<dim3(E / 128, MROWS / 128), 256, 0, stream>>>(
        at16, wo16, bout, out, nullptr, nullptr, nullptr, nullptr, nullptr, 0, E, E);
}

// Round 9
// 285.774 us; speedup vs baseline: 1.0370x; 1.0370x over previous
//
#include <hip/hip_runtime.h>
#include <math.h>

#define B 4
#define L 2048
#define E 1024
#define H 16
#define HD 64
#define MROWS (B*L)      // 8192
#define E3 (3*E)         // 3072

using bf16x8   = __attribute__((ext_vector_type(8))) short;
using f16x8    = __attribute__((ext_vector_type(8))) _Float16;
using floatx4  = __attribute__((ext_vector_type(4))) float;
using floatx16 = __attribute__((ext_vector_type(16))) float;

__device__ inline ushort f2bf(float x) {
    uint u = __float_as_uint(x);
    u += 0x7FFF + ((u >> 16) & 1);     // RNE
    return (ushort)(u >> 16);
}
__device__ inline float bf2f(ushort h) { return __uint_as_float(((uint)h) << 16); }
__device__ inline ushort f2h(float x) { _Float16 h = (_Float16)x; return *(ushort*)&h; }

#if __has_builtin(__builtin_amdgcn_exp2f)
#define EXP2F(x) __builtin_amdgcn_exp2f(x)
#else
#define EXP2F(x) exp2f(x)
#endif

__device__ inline void async16(const void* g, void* l) {
    __builtin_amdgcn_global_load_lds(
        (const __attribute__((address_space(1))) uint*)g,
        (__attribute__((address_space(3))) uint*)l, 16, 0, 0);
}

// pack two fp32 -> {bf16(odd),bf16(even)} with RTZ in one v_perm
__device__ inline uint pack_rtz(float odd, float even) {
    return __builtin_amdgcn_perm(__float_as_uint(odd), __float_as_uint(even), 0x07060302u);
}

// ------------------------------------------------------------------
// fused fp32 -> fp16 convert of x | Wqkv | Wout (one launch)
// ------------------------------------------------------------------
#define N1Q ((size_t)MROWS * E / 4)        // x quads
#define N2Q ((size_t)E3 * E / 4)           // Wqkv quads
#define N3Q ((size_t)E * E / 4)            // Wout quads
__global__ __launch_bounds__(256) void cvt_all(
        const float* __restrict__ x, const float* __restrict__ wq,
        const float* __restrict__ wo, ushort* __restrict__ x16,
        ushort* __restrict__ wq16, ushort* __restrict__ wo16)
{
    size_t i = (size_t)blockIdx.x * 256 + threadIdx.x;
    const float* src; ushort* dst; size_t j;
    if (i < N1Q)                  { src = x;  dst = x16;  j = i; }
    else if (i < N1Q + N2Q)       { src = wq; dst = wq16; j = i - N1Q; }
    else                          { src = wo; dst = wo16; j = i - N1Q - N2Q; }
    float4 v = ((const float4*)src)[j];
    ushort4 o;
    o.x = f2h(v.x); o.y = f2h(v.y); o.z = f2h(v.z); o.w = f2h(v.w);
    ((ushort4*)dst)[j] = o;
}

// ------------------------------------------------------------------
// Single-pass fp16 MFMA GEMM (R0 harness-proven, byte-identical):
// async double-buffered K-loop, 128x128 tile, BK=32, 256 thr = 4 waves.
// MODE 1 epilogue: bias + RoPE -> swizzled q/k + sigma'd v^T (bf16).
// MODE 2 epilogue: bias, fp32 row-major out.
// ------------------------------------------------------------------
template<int MODE>
__global__ __launch_bounds__(256) void gemm_f16(
        const ushort* __restrict__ A16, const ushort* __restrict__ B16,
        const float* __restrict__ bias, float* __restrict__ Cf,
        ushort* __restrict__ qh, ushort* __restrict__ kh, ushort* __restrict__ vT,
        const float* __restrict__ cosT, const float* __restrict__ sinT,
        int Ndim, int Kdim)
{
    __shared__ ushort lds[2][8192];   // dbuf of (A tile | B tile)

    const int tid = threadIdx.x;
    const int w = tid >> 6, lane = tid & 63;
    const int g = lane >> 4, c = lane & 15;
    const int m0 = blockIdx.y * 128, n0 = blockIdx.x * 128;
    const int wm = w & 1, wn = w >> 1;

    const int rl0 = lane >> 2;
    const int jsw = (lane & 3) ^ ((lane >> 3) & 3);
    const ushort* gbase = (w < 2) ? A16 + (size_t)(m0 + 64 * (w & 1)) * Kdim
                                  : B16 + (size_t)(n0 + 64 * (w & 1)) * Kdim;
    const ushort* lanesrc = gbase + (size_t)rl0 * Kdim + jsw * 8;
    const int ldoff = (w >> 1) * 4096 + (w & 1) * 2048;

    floatx4 acc[4][4];
#pragma unroll
    for (int a = 0; a < 4; ++a)
#pragma unroll
        for (int bq = 0; bq < 4; ++bq) acc[a][bq] = (floatx4){0.f, 0.f, 0.f, 0.f};

    const int swz  = (g ^ ((c >> 1) & 3)) * 8;
    const int arow = wm * 2048 + c * 32;
    const int brow = 4096 + wn * 2048 + c * 32;

    // prologue: stage k-tile 0 into buf 0
#pragma unroll
    for (int p = 0; p < 4; ++p)
        async16(lanesrc + (size_t)p * 16 * Kdim, &lds[0][ldoff + p * 512]);

    const int NK = Kdim >> 5;   // 32
    for (int kk = 0; kk < NK; ++kk) {
        const int pb = kk & 1;
        __syncthreads();   // drains the loads targeting buf pb; syncs waves

        // prefetch k-tile kk+1 into the other buffer (flies during compute)
        if (kk + 1 < NK) {
            const ushort* ns = lanesrc + (size_t)(kk + 1) * 32;
#pragma unroll
            for (int p = 0; p < 4; ++p)
                async16(ns + (size_t)p * 16 * Kdim, &lds[pb ^ 1][ldoff + p * 512]);
        }

        const ushort* cur = &lds[pb][0];
        f16x8 af[4], bf[4];
#pragma unroll
        for (int t = 0; t < 4; ++t) {
            af[t] = *(const f16x8*)&cur[arow + t * 512 + swz];
            bf[t] = *(const f16x8*)&cur[brow + t * 512 + swz];
        }
#pragma unroll
        for (int mt = 0; mt < 4; ++mt)
#pragma unroll
            for (int nt = 0; nt < 4; ++nt)
                acc[mt][nt] = __builtin_amdgcn_mfma_f32_16x16x32_f16(af[mt], bf[nt], acc[mt][nt], 0, 0, 0);
    }

    // ---- epilogue; C/D: row = g*4+i, col = c (per 16x16 tile) ----
    const int colbase = n0 + wn * 64;
#pragma unroll
    for (int mt = 0; mt < 4; ++mt) {
        const int rowb = m0 + wm * 64 + mt * 16 + g * 4;
        if constexpr (MODE == 2) {
#pragma unroll
            for (int i = 0; i < 4; ++i) {
                const int row = rowb + i;
#pragma unroll
                for (int nt = 0; nt < 4; ++nt) {
                    const int col = colbase + nt * 16 + c;
                    Cf[(size_t)row * Ndim + col] = acc[mt][nt][i] + bias[col];
                }
            }
        } else {
            const int sec = colbase >> 10;             // 0=q 1=k 2=v
            const int hg  = (colbase & 1023) >> 6;
#pragma unroll
            for (int i = 0; i < 4; ++i) {
                const int row = rowb + i;
                const int bb = row >> 11;
                const int l  = row & (L - 1);
                if (sec < 2) {
                    ushort* dst = (sec == 0 ? qh : kh) + ((size_t)(bb * H + hg) * L + l) * HD;
                    const int sw = l & 7;
                    // q carries softmax scale AND log2e for the exp2 softmax
                    const float qs = (sec == 0) ? 0.18033688f : 1.0f;
#pragma unroll
                    for (int nt = 0; nt < 2; ++nt) {
                        const int d  = nt * 16 + c;
                        const int d2 = d + 32;
                        float v1 = acc[mt][nt][i]     + bias[colbase + d];
                        float v2 = acc[mt][nt + 2][i] + bias[colbase + d2];
                        float cs = cosT[l * 32 + d], sn = sinT[l * 32 + d];
                        dst[(((d  >> 3) ^ sw) << 3) | (d  & 7)] = f2bf((v1 * cs - v2 * sn) * qs);
                        dst[(((d2 >> 3) ^ sw) << 3) | (d2 & 7)] = f2bf((v1 * sn + v2 * cs) * qs);
                    }
                } else {
                    // sigma: swap bits 2,3 of kpos; then group-swizzle by d&7
                    const int lp = (l & ~12) | ((l & 4) << 1) | ((l & 8) >> 1);
                    const int intile = ((((lp >> 3) & 7)) << 3);
#pragma unroll
                    for (int nt = 0; nt < 4; ++nt) {
                        const int d = nt * 16 + c;
                        float v = acc[mt][nt][i] + bias[colbase + d];
                        size_t idx = ((size_t)(bb * H + hg) * HD + d) * L
                                   + (l & ~63) + (intile ^ ((d & 7) << 3)) + (lp & 7);
                        vT[idx] = f2bf(v);
                    }
                }
            }
        }
    }
}

// ------------------------------------------------------------------
// Flash attention v5 = R0's flash (no setprio) with ONE change:
// halfrow-interleaved K/V LDS layout to kill the measured 8.39M
// conflict-cycles (row stride was 32 dw == 0 mod 32 banks).
//   LDS tile = 128 halfrows x 32 ushorts. halfrow hr = row + 64*hi
//   (row = kpos for K / d for V; hi = d-group msb). Position
//   p in 0..3 holds content group dg with dg&3 = p ^ ((row>>1)&3),
//   dg>>2 = hi. Implemented via pre-swizzled per-lane STAGING SOURCES
//   (global_load_lds dest stays linear); global layouts unchanged.
//   Bank pattern of frag reads == GEMM's proven zero-conflict pattern.
// ------------------------------------------------------------------
__global__ __launch_bounds__(256, 4) void flash_mfma4(
        const ushort* __restrict__ qh, const ushort* __restrict__ kh,
        const ushort* __restrict__ vT, ushort* __restrict__ attn16)
{
    __shared__ ushort Ks[2][4096];
    __shared__ ushort Vt[2][4096];

    const int tid  = threadIdx.x;
    const int w    = tid >> 6;
    const int lane = tid & 63;
    const int h    = lane >> 5;
    const int n    = lane & 31;
    const int b    = blockIdx.x >> 4;
    const int hd   = blockIdx.x & 15;
    const int q0   = blockIdx.y * 128;

    const ushort* khead = kh + (size_t)(b * H + hd) * L * HD;
    const ushort* vhead = vT + (size_t)(b * H + hd) * HD * L;

    const int q = q0 + 32 * w + n;
    const ushort* qrow = qh + ((size_t)(b * H + hd) * L + q) * HD;
    bf16x8 aq[4];
#pragma unroll
    for (int kd = 0; kd < 4; ++kd)
        aq[kd] = *(const bf16x8*)&qrow[((2 * kd + h) ^ (q & 7)) << 3];

    // ---- staging sources, halfrow-interleaved bijection ----
    // call cc (0..7): slot = 64*cc + lane (16B units) = 4*hr + p with
    //   hr = 16*cc + (lane>>2), p = lane&3.
    //   row = hr&63, hi = hr>>6; dg = (hi<<2) | (p ^ ((lane>>3)&3))
    //   [(lane>>3)&3 == (hr>>1)&3]; gpos = dg ^ (row&7) (global swizzle).
    const int wk   = w & 1;
    const int l2   = lane >> 2;
    const int dglo = (lane & 3) ^ ((lane >> 3) & 3);
    const ushort* pK[4]; const ushort* pV[4];
#pragma unroll
    for (int j = 0; j < 4; ++j) {
        const int cc   = 4 * wk + j;
        const int hr   = 16 * cc + l2;
        const int row  = hr & 63;
        const int hi   = hr >> 6;
        const int dg   = (hi << 2) | dglo;
        const int gpos = dg ^ (l2 & 7);
        pK[j] = khead + row * 64 + gpos * 8;
        pV[j] = vhead + (size_t)row * L + gpos * 8;
    }

    const int NIT = L / 64;   // 32
    if (w < 2) {
#pragma unroll
        for (int j = 0; j < 4; ++j)
            async16(pK[j], &Ks[0][(4 * wk + j) * 512]);
    } else {
#pragma unroll
        for (int j = 0; j < 4; ++j)
            async16(pV[j], &Vt[0][(4 * wk + j) * 512]);
    }

    float l_i = 0.f;
    floatx16 o[2];
    o[0] = (floatx16)(0.f);
    o[1] = (floatx16)(0.f);

    const int sw13 = (n >> 1) & 3;   // read-side position swizzle

    for (int it = 0; it < NIT; ++it) {
        const int p = it & 1;
        __syncthreads();

        if (it + 1 < NIT) {
            if (w < 2) {
#pragma unroll
                for (int j = 0; j < 4; ++j)
                    async16(pK[j] + (size_t)(it + 1) * 4096, &Ks[p ^ 1][(4 * wk + j) * 512]);
            } else {
#pragma unroll
                for (int j = 0; j < 4; ++j)
                    async16(pV[j] + (size_t)(it + 1) * 64, &Vt[p ^ 1][(4 * wk + j) * 512]);
            }
        }

        const ushort* KsC = Ks[p];
        const ushort* VtC = Vt[p];

#pragma unroll
        for (int js = 0; js < 2; ++js) {
            floatx16 s = (floatx16)(-16.0f);
#pragma unroll
            for (int kd = 0; kd < 4; ++kd) {
                // dg = 2kd+h: hr = (32js+n) + 64*(kd>>1),
                // pos = (2*(kd&1)+h) ^ ((n>>1)&3)
                bf16x8 kf = *(const bf16x8*)&KsC[
                    (32 * js + n + ((kd >> 1) << 6)) * 32
                    + (((2 * (kd & 1) + h) ^ sw13) << 3)];
                s = __builtin_amdgcn_mfma_f32_32x32x16_bf16(kf, aq[kd], s, 0, 0, 0);
            }

            float pv[16];
            float rs = 0.f;
#pragma unroll
            for (int rr = 0; rr < 4; ++rr) {
                float p0 = EXP2F(s[4 * rr + 0]);
                float p1 = EXP2F(s[4 * rr + 1]);
                float p2 = EXP2F(s[4 * rr + 2]);
                float p3 = EXP2F(s[4 * rr + 3]);
                pv[4 * rr + 0] = p0; pv[4 * rr + 1] = p1;
                pv[4 * rr + 2] = p2; pv[4 * rr + 3] = p3;
                rs += (p0 + p1) + (p2 + p3);
            }
            l_i += rs;

#pragma unroll
            for (int f = 0; f < 2; ++f) {
                uint bu[4];
                bu[0] = pack_rtz(pv[8 * f + 1], pv[8 * f + 0]);
                bu[1] = pack_rtz(pv[8 * f + 3], pv[8 * f + 2]);
                bu[2] = pack_rtz(pv[8 * f + 5], pv[8 * f + 4]);
                bu[3] = pack_rtz(pv[8 * f + 7], pv[8 * f + 6]);
                bf16x8 bp = *(const bf16x8*)&bu[0];
#pragma unroll
                for (int nt = 0; nt < 2; ++nt) {
                    // kg = 4js+2f+h: hr = (32nt+n) + 64*js,
                    // pos = (2f+h) ^ ((n>>1)&3)
                    bf16x8 vf = *(const bf16x8*)&VtC[
                        (32 * nt + n + (js << 6)) * 32
                        + (((2 * f + h) ^ sw13) << 3)];
                    o[nt] = __builtin_amdgcn_mfma_f32_32x32x16_bf16(vf, bp, o[nt], 0, 0, 0);
                }
            }
        }
    }

    const float l_tot = l_i + __shfl_xor(l_i, 32, 64);
    const float inv = 1.f / l_tot;
    const size_t rowbase = ((size_t)(b * L + q)) * E + hd * HD;
#pragma unroll
    for (int nt = 0; nt < 2; ++nt)
#pragma unroll
        for (int rr = 0; rr < 4; ++rr) {
            const int d0 = 32 * nt + 8 * rr + 4 * h;
            ushort h0 = f2h(o[nt][4 * rr + 0] * inv);
            ushort h1 = f2h(o[nt][4 * rr + 1] * inv);
            ushort h2 = f2h(o[nt][4 * rr + 2] * inv);
            ushort h3 = f2h(o[nt][4 * rr + 3] * inv);
            uint2 hw;
            hw.x = (uint)h0 | ((uint)h1 << 16);
            hw.y = (uint)h2 | ((uint)h3 << 16);
            *(uint2*)&attn16[rowbase + d0] = hw;
        }
}

extern "C" void kernel_launch(void* const* d_in, const int* in_sizes, int n_in,
                              void* d_out, int out_size, void* d_ws, size_t ws_size,
                              hipStream_t stream) {
    const float* x    = (const float*)d_in[0];
    const float* cosT = (const float*)d_in[1];
    const float* sinT = (const float*)d_in[2];
    const float* Wqkv = (const float*)d_in[3];
    const float* bqkv = (const float*)d_in[4];
    const float* Wout = (const float*)d_in[5];
    const float* bout = (const float*)d_in[6];
    float* out = (float*)d_out;

    const size_t NX = (size_t)MROWS * E;
    ushort* us   = (ushort*)d_ws;
    ushort* qh   = us;                        // [B,H,L,HD] roped+scaled q (bf16, swz)
    ushort* kh   = us + NX;                   // [B,H,L,HD] roped k (bf16, swz)
    ushort* vTp  = us + 2 * NX;               // [B,H,HD,L] v^T (bf16, sigma+swz)
    ushort* x16  = us + 3 * NX;               // x fp16
    ushort* at16 = us + 4 * NX;               // attn fp16
    ushort* wq16 = us + 5 * NX;               // Wqkv fp16
    ushort* wo16 = wq16 + (size_t)E3 * E;     // Wout fp16

    const int cvt_blocks = (int)((N1Q + N2Q + N3Q + 255) / 256);
    cvt_all<<<cvt_blocks, 256, 0, stream>>>(x, Wqkv, Wout, x16, wq16, wo16);

    gemm_f16<1><<<dim3(E3 / 128, MROWS / 128), 256, 0, stream>>>(
        x16, wq16, bqkv, nullptr, qh, kh, vTp, cosT, sinT, E3, E);

    flash_mfma4<<<dim3(B * H, L / 128), 256, 0, stream>>>(qh, kh, vTp, at16);

    gemm_f16<2><<<dim3(E / 128, MROWS / 128), 256, 0, stream>>>(
        at16, wo16, bout, out, nullptr, nullptr, nullptr, nullptr, nullptr, E, E);
}